// Round 8
// baseline (121.380 us; speedup 1.0000x reference)
//
#include <hip/hip_runtime.h>
#include <hip/hip_bf16.h>

typedef unsigned short u16;
typedef __attribute__((ext_vector_type(8))) short frag_ab;   // 8 bf16 (4 VGPRs)
typedef __attribute__((ext_vector_type(4))) float f32x4;     // 4 fp32 acc
typedef _Float16 f16;
typedef __attribute__((ext_vector_type(4))) _Float16 f16x4;  // 4 f16 (2 VGPRs)

#define LOG2E 1.44269504088896f

__device__ __forceinline__ float fast_exp2(float x) {
    return __builtin_amdgcn_exp2f(x);   // v_exp_f32 (D = 2^S0)
}

__device__ __forceinline__ void gload_lds16(const u16* g, u16* s) {
    __builtin_amdgcn_global_load_lds((const __attribute__((address_space(1))) void*)g,
                                     (__attribute__((address_space(3))) void*)s, 16, 0, 0);
}
__device__ __forceinline__ void gload_lds16h(const f16* g, f16* s) {
    __builtin_amdgcn_global_load_lds((const __attribute__((address_space(1))) void*)g,
                                     (__attribute__((address_space(3))) void*)s, 16, 0, 0);
}

// ---------------------------------------------------------------------------
// Fused prep: blocks [0,2048): x transpose+cast; [2048,3072): W converts.
// ---------------------------------------------------------------------------
__global__ __launch_bounds__(256) void prep_kernel(
    const float* __restrict__ x, __hip_bfloat16* __restrict__ xs_bf,
    const float* __restrict__ Wp, const float* __restrict__ Wo,
    __hip_bfloat16* __restrict__ w_bf)
{
    __shared__ float tile[32][33];
    const int tid = threadIdx.x;
    const int id = blockIdx.x;
    if (id < 2048) {
        const int i0 = (id & 31) * 32;
        const int c0 = ((id >> 5) & 15) * 32;
        const int b  = id >> 9;
        const int tx = tid & 31, ty = tid >> 5;
        const float* xp = x + ((size_t)b * 512 + c0) * 1024 + i0;
        #pragma unroll
        for (int r = ty; r < 32; r += 8)
            tile[r][tx] = xp[(size_t)r * 1024 + tx];
        __syncthreads();
        __hip_bfloat16* op = xs_bf + ((size_t)b * 1024 + i0) * 512 + c0;
        #pragma unroll
        for (int r = ty; r < 32; r += 8)
            op[(size_t)r * 512 + tx] = __float2bfloat16(tile[tx][r]);
    } else {
        const int t = (id - 2048) * 256 + tid;
        const int i4 = t * 4;
        const float* src = (i4 < 786432) ? (Wp + i4) : (Wo + (i4 - 786432));
        const float4 v = *(const float4*)src;
        ushort4 o;
        o.x = __bfloat16_as_ushort(__float2bfloat16(v.x));
        o.y = __bfloat16_as_ushort(__float2bfloat16(v.y));
        o.z = __bfloat16_as_ushort(__float2bfloat16(v.z));
        o.w = __bfloat16_as_ushort(__float2bfloat16(v.w));
        *(ushort4*)((u16*)w_bf + i4) = o;
    }
}

// ---------------------------------------------------------------------------
// qkv^T GEMM, 64-ch x 128-pix tiles, BK=128 (4 k-iters, 8 barriers total).
// Block's 64-ch window is exactly one of {Q,K,V} of one head (block-uniform).
// ---------------------------------------------------------------------------
__global__ __launch_bounds__(256) void qkv_gemm_kernel(
    const u16* __restrict__ Wpb, const u16* __restrict__ xsb,
    const float* __restrict__ bp,
    u16* __restrict__ Qb, u16* __restrict__ Kb, f16* __restrict__ VtT)
{
    __shared__ u16 lds[24576];      // As 64x128 | Bs 128x128 = 48 KB; reused as Tr[128][72]
    u16* As = lds;
    u16* Bs = lds + 8192;
    f32x4 acc[2][4];
    #pragma unroll
    for (int mt = 0; mt < 2; ++mt)
        #pragma unroll
        for (int nt = 0; nt < 4; ++nt)
            { acc[mt][nt][0]=0.f; acc[mt][nt][1]=0.f; acc[mt][nt][2]=0.f; acc[mt][nt][3]=0.f; }
    const int m0 = blockIdx.x * 64;    // ch
    const int n0 = blockIdx.y * 128;   // pix

    const int tid = threadIdx.x;
    const int lane = tid & 63, quad = lane >> 4, l16 = lane & 15;
    const int wr = ((tid >> 7) & 1) * 32, wc = ((tid >> 6) & 1) * 64;
    const int srow = tid >> 4;          // 0..15
    const int scol = (tid & 15) * 8;    // 0..120 (16B per thread)

    for (int k0 = 0; k0 < 512; k0 += 128) {
        __syncthreads();
        #pragma unroll
        for (int p = 0; p < 4; ++p) {
            const int r = srow + p * 16;
            gload_lds16(Wpb + (size_t)(m0 + r) * 512 + k0 + scol, As + r * 128 + scol);
        }
        #pragma unroll
        for (int p = 0; p < 8; ++p) {
            const int r = srow + p * 16;
            gload_lds16(xsb + (size_t)(n0 + r) * 512 + k0 + scol, Bs + r * 128 + scol);
        }
        __syncthreads();
        #pragma unroll
        for (int ks = 0; ks < 4; ++ks) {
            frag_ab a[2], b[4];
            #pragma unroll
            for (int mt = 0; mt < 2; ++mt)
                a[mt] = *(const frag_ab*)(As + (wr + mt * 16 + l16) * 128 + ks * 32 + quad * 8);
            #pragma unroll
            for (int nt = 0; nt < 4; ++nt)
                b[nt] = *(const frag_ab*)(Bs + (wc + nt * 16 + l16) * 128 + ks * 32 + quad * 8);
            #pragma unroll
            for (int mt = 0; mt < 2; ++mt)
                #pragma unroll
                for (int nt = 0; nt < 4; ++nt)
                    acc[mt][nt] = __builtin_amdgcn_mfma_f32_16x16x32_bf16(a[mt], b[nt], acc[mt][nt], 0, 0, 0);
        }
    }

    const int h = blockIdx.x / 3, part = blockIdx.x % 3;   // block-uniform
    const int b = blockIdx.y >> 3, ipb = (blockIdx.y & 7) * 128;
    const size_t bh = (size_t)(b * 8 + h);

    if (part < 2) {
        const float scale = (part == 0) ? (0.125f * LOG2E) : 1.0f;
        __syncthreads();            // all waves done with As/Bs
        u16* T = lds;               // [pix 128][ch 64 pad 72]
        #pragma unroll
        for (int nt = 0; nt < 4; ++nt) {
            const int px = wc + nt * 16 + l16;
            #pragma unroll
            for (int mt = 0; mt < 2; ++mt) {
                const int cb = m0 + wr + mt * 16 + quad * 4;
                ushort4 pk;
                pk.x = __bfloat16_as_ushort(__float2bfloat16((acc[mt][nt][0] + bp[cb + 0]) * scale));
                pk.y = __bfloat16_as_ushort(__float2bfloat16((acc[mt][nt][1] + bp[cb + 1]) * scale));
                pk.z = __bfloat16_as_ushort(__float2bfloat16((acc[mt][nt][2] + bp[cb + 2]) * scale));
                pk.w = __bfloat16_as_ushort(__float2bfloat16((acc[mt][nt][3] + bp[cb + 3]) * scale));
                *(ushort4*)&T[px * 72 + wr + mt * 16 + quad * 4] = pk;
            }
        }
        __syncthreads();
        u16* dst = (part == 0 ? Qb : Kb);
        #pragma unroll
        for (int p = 0; p < 4; ++p) {
            const int row = p * 32 + (tid >> 3);
            const int ch8 = (tid & 7) * 8;
            uint4 rv = *(uint4*)&T[row * 72 + ch8];
            *(uint4*)(dst + ((bh * 1024 + ipb + row) << 6) + ch8) = rv;
        }
    } else {
        f16* dst = VtT + bh * 65536;   // [jc 128][d 64][j8 8]
        #pragma unroll
        for (int mt = 0; mt < 2; ++mt) {
            #pragma unroll
            for (int r = 0; r < 4; ++r) {
                const int d = wr + mt * 16 + quad * 4 + r;
                const float bias = bp[m0 + d];
                #pragma unroll
                for (int nt = 0; nt < 4; ++nt) {
                    const int j = ipb + wc + nt * 16 + l16;
                    dst[(size_t)(j >> 3) * 512 + d * 8 + (j & 7)] =
                        (f16)(acc[mt][nt][r] + bias);
                }
            }
        }
    }
}

// ---------------------------------------------------------------------------
// Attention: block = (bh, 64-i tile), 4 waves split j (r6 structure).
// LDS cut 68.6 -> ~33.5 KB by overlaying the combine staging onto the dead
// Ks/Vs pool, combined in 4 phases of 16 i-rows -> 3 blocks/CU.
// ---------------------------------------------------------------------------
__global__ __launch_bounds__(256) void attn_kernel(
    const u16* __restrict__ Qb, const u16* __restrict__ Kb,
    const f16* __restrict__ VtT, __hip_bfloat16* __restrict__ resb)
{
    __shared__ u16 pool[16384];           // 32 KB: Ks[0:8192] | Vs[8192:16384]
    __shared__ float Lpart[4][4][16];     // 1 KB [w][ig][i]
    u16* Ks = pool;                       // [j_local 128][d 64]
    f16* Vs = (f16*)(pool + 8192);        // [chunk 16][d 64][j8 8]
    const int bh = blockIdx.x;
    const int it = blockIdx.y;            // 64-row i tile, 0..15
    const int tid = threadIdx.x;
    const int w = tid >> 6, lane = tid & 63, quad = lane >> 4, l16 = lane & 15;
    const int srow = tid >> 3, scol = (tid & 7) * 8;

    const u16* Qp = Qb + (size_t)bh * 65536;
    const u16* Kp = Kb + (size_t)bh * 65536;
    const f16* Vp = VtT + (size_t)bh * 65536;

    frag_ab bq[4][2];
    #pragma unroll
    for (int ig = 0; ig < 4; ++ig) {
        const u16* qptr = Qp + (size_t)(it * 64 + ig * 16 + l16) * 64 + quad * 8;
        bq[ig][0] = *(const frag_ab*)(qptr);
        bq[ig][1] = *(const frag_ab*)(qptr + 32);
    }

    f32x4 o[4][4];
    #pragma unroll
    for (int ig = 0; ig < 4; ++ig)
        #pragma unroll
        for (int dt = 0; dt < 4; ++dt)
            { o[ig][dt][0]=0.f; o[ig][dt][1]=0.f; o[ig][dt][2]=0.f; o[ig][dt][3]=0.f; }
    float l_acc[4] = {0.f, 0.f, 0.f, 0.f};

    for (int jt = 0; jt < 8; ++jt) {
        __syncthreads();
        #pragma unroll
        for (int p = 0; p < 4; ++p) {
            const int r = srow + p * 32;
            gload_lds16(Kp + (size_t)(jt * 128 + r) * 64 + scol, Ks + r * 64 + scol);
        }
        #pragma unroll
        for (int p = 0; p < 4; ++p) {
            const int c = w * 4 + p;
            gload_lds16h(Vp + (size_t)((jt * 16 + c) * 64 + lane) * 8,
                         Vs + (size_t)(c * 64 + lane) * 8);
        }
        __syncthreads();

        frag_ab ka[2][2];
        #pragma unroll
        for (int mt = 0; mt < 2; ++mt) {
            const u16* kp = Ks + (w * 32 + mt * 16 + l16) * 64 + quad * 8;
            ka[mt][0] = *(const frag_ab*)(kp);
            ka[mt][1] = *(const frag_ab*)(kp + 32);
        }
        f16x4 va[4][2];
        #pragma unroll
        for (int ks = 0; ks < 2; ++ks) {
            const f16* vrow = Vs + (size_t)(w * 4 + ks * 2 + (quad >> 1)) * 512 + (quad & 1) * 4;
            #pragma unroll
            for (int dt = 0; dt < 4; ++dt)
                va[dt][ks] = *(const f16x4*)(vrow + (dt * 16 + l16) * 8);
        }
        #pragma unroll
        for (int ig = 0; ig < 4; ++ig) {
            f32x4 st0 = {0.f, 0.f, 0.f, 0.f}, st1 = {0.f, 0.f, 0.f, 0.f};
            st0 = __builtin_amdgcn_mfma_f32_16x16x32_bf16(ka[0][0], bq[ig][0], st0, 0, 0, 0);
            st0 = __builtin_amdgcn_mfma_f32_16x16x32_bf16(ka[0][1], bq[ig][1], st0, 0, 0, 0);
            st1 = __builtin_amdgcn_mfma_f32_16x16x32_bf16(ka[1][0], bq[ig][0], st1, 0, 0, 0);
            st1 = __builtin_amdgcn_mfma_f32_16x16x32_bf16(ka[1][1], bq[ig][1], st1, 0, 0, 0);
            f16x4 p0, p1;
            float s = 0.f;
            #pragma unroll
            for (int r = 0; r < 4; ++r) {
                const float e0 = fast_exp2(st0[r]);
                const float e1 = fast_exp2(st1[r]);
                s += e0 + e1;
                p0[r] = (f16)e0;
                p1[r] = (f16)e1;
            }
            l_acc[ig] += s;
            #pragma unroll
            for (int dt = 0; dt < 4; ++dt) {
                o[ig][dt] = __builtin_amdgcn_mfma_f32_16x16x16f16(va[dt][0], p0, o[ig][dt], 0, 0, 0);
                o[ig][dt] = __builtin_amdgcn_mfma_f32_16x16x16f16(va[dt][1], p1, o[ig][dt], 0, 0, 0);
            }
        }
    }
    #pragma unroll
    for (int ig = 0; ig < 4; ++ig) {
        l_acc[ig] += __shfl_xor(l_acc[ig], 16);
        l_acc[ig] += __shfl_xor(l_acc[ig], 32);
    }
    if (lane < 16) {
        #pragma unroll
        for (int ig = 0; ig < 4; ++ig)
            Lpart[w][ig][lane] = l_acc[ig];
    }

    // 4-phase combine overlaid on pool: Op[w][16][68] fp32 = 17.4 KB
    float* Op = (float*)pool;
    const int bb = bh >> 3, hh = bh & 7;
    const int ri = tid >> 4, d0f = (tid & 15) * 4;
    #pragma unroll
    for (int ph = 0; ph < 4; ++ph) {
        __syncthreads();   // ph0: Ks/Vs reads + Lpart done; else: prior reads done
        #pragma unroll
        for (int dt = 0; dt < 4; ++dt)
            *(f32x4*)&Op[(w * 16 + l16) * 68 + dt * 16 + quad * 4] = o[ph][dt];
        __syncthreads();
        f32x4 s = *(const f32x4*)&Op[ri * 68 + d0f];
        #pragma unroll
        for (int ww = 1; ww < 4; ++ww)
            s += *(const f32x4*)&Op[(ww * 16 + ri) * 68 + d0f];
        const float linv = 1.f / (Lpart[0][ph][ri] + Lpart[1][ph][ri] +
                                  Lpart[2][ph][ri] + Lpart[3][ph][ri]);
        u16 pk[4];
        #pragma unroll
        for (int e = 0; e < 4; ++e)
            pk[e] = __bfloat16_as_ushort(__float2bfloat16(s[e] * linv));
        u16* orow = (u16*)resb +
            ((size_t)(bb * 1024 + it * 64 + ph * 16 + ri)) * 512 + hh * 64 + d0f;
        *(uint2*)orow = *(uint2*)pk;
    }
}

// ---------------------------------------------------------------------------
// out^T GEMM, 64x64 tiles, BK=128 (4 k-iters):
// D[c][pix] = Wo[c,:].res[pix,:] + bo[c] + x[b][c][pix]
// ---------------------------------------------------------------------------
__global__ __launch_bounds__(256) void out_gemm_kernel(
    const u16* __restrict__ Wob, const u16* __restrict__ resb,
    const float* __restrict__ bo, const float* __restrict__ x,
    float* __restrict__ out)
{
    __shared__ u16 As[64 * 128];   // 16 KB
    __shared__ u16 Bs[64 * 128];   // 16 KB
    f32x4 acc[2][2];
    #pragma unroll
    for (int mt = 0; mt < 2; ++mt)
        #pragma unroll
        for (int nt = 0; nt < 2; ++nt)
            { acc[mt][nt][0]=0.f; acc[mt][nt][1]=0.f; acc[mt][nt][2]=0.f; acc[mt][nt][3]=0.f; }
    const int m0 = blockIdx.x * 64;   // c
    const int n0 = blockIdx.y * 64;   // pix

    const int tid = threadIdx.x;
    const int lane = tid & 63, quad = lane >> 4, l16 = lane & 15;
    const int wr = ((tid >> 7) & 1) * 32, wc = ((tid >> 6) & 1) * 32;
    const int srow = tid >> 4;          // 0..15
    const int scol = (tid & 15) * 8;    // 0..120

    for (int k0 = 0; k0 < 512; k0 += 128) {
        __syncthreads();
        #pragma unroll
        for (int p = 0; p < 4; ++p) {
            const int r = srow + p * 16;
            gload_lds16(Wob + (size_t)(m0 + r) * 512 + k0 + scol, As + r * 128 + scol);
            gload_lds16(resb + (size_t)(n0 + r) * 512 + k0 + scol, Bs + r * 128 + scol);
        }
        __syncthreads();
        #pragma unroll
        for (int ks = 0; ks < 4; ++ks) {
            frag_ab a[2], b[2];
            #pragma unroll
            for (int mt = 0; mt < 2; ++mt)
                a[mt] = *(const frag_ab*)(As + (wr + mt * 16 + l16) * 128 + ks * 32 + quad * 8);
            #pragma unroll
            for (int nt = 0; nt < 2; ++nt)
                b[nt] = *(const frag_ab*)(Bs + (wc + nt * 16 + l16) * 128 + ks * 32 + quad * 8);
            #pragma unroll
            for (int mt = 0; mt < 2; ++mt)
                #pragma unroll
                for (int nt = 0; nt < 2; ++nt)
                    acc[mt][nt] = __builtin_amdgcn_mfma_f32_16x16x32_bf16(a[mt], b[nt], acc[mt][nt], 0, 0, 0);
        }
    }

    #pragma unroll
    for (int nt = 0; nt < 2; ++nt) {
        const int pix = n0 + wc + nt * 16 + l16;
        const int b = pix >> 10, ip = pix & 1023;
        #pragma unroll
        for (int mt = 0; mt < 2; ++mt) {
            #pragma unroll
            for (int r = 0; r < 4; ++r) {
                const int c = m0 + wr + mt * 16 + quad * 4 + r;
                const size_t oidx = (((size_t)b * 512 + c) << 10) + ip;
                out[oidx] = acc[mt][nt][r] + bo[c] + x[oidx];
            }
        }
    }
}

// ---------------------------------------------------------------------------
extern "C" void kernel_launch(void* const* d_in, const int* in_sizes, int n_in,
                              void* d_out, int out_size, void* d_ws, size_t ws_size,
                              hipStream_t stream)
{
    const float* x  = (const float*)d_in[0];   // [4,512,32,32]
    const float* Wp = (const float*)d_in[1];   // [1536,512]
    const float* bp = (const float*)d_in[2];   // [1536]
    const float* Wo = (const float*)d_in[3];   // [512,512]
    const float* bo = (const float*)d_in[4];   // [512]
    float* out = (float*)d_out;

    char* ws = (char*)d_ws;
    size_t off = 0;
    auto carve = [&](size_t bytes) -> void* {
        void* ptr = ws + off;
        off += (bytes + 255) & ~(size_t)255;
        return ptr;
    };
    __hip_bfloat16* xs_bf = (__hip_bfloat16*)carve((size_t)4096 * 512 * 2);
    __hip_bfloat16* Wp_bf = (__hip_bfloat16*)carve((size_t)1536 * 512 * 2);  // Wo_bf contiguous after
    __hip_bfloat16* Wo_bf = (__hip_bfloat16*)carve((size_t)512 * 512 * 2);
    u16*            Qb    = (u16*)carve((size_t)32 * 1024 * 64 * 2);
    u16*            Kb    = (u16*)carve((size_t)32 * 1024 * 64 * 2);
    f16*            VtT   = (f16*)carve((size_t)32 * 1024 * 64 * 2);
    __hip_bfloat16* resb  = (__hip_bfloat16*)carve((size_t)4096 * 512 * 2);

    prep_kernel<<<dim3(3072), 256, 0, stream>>>(x, xs_bf, Wp, Wo, Wp_bf);
    qkv_gemm_kernel<<<dim3(24, 32), 256, 0, stream>>>(
        (const u16*)Wp_bf, (const u16*)xs_bf, bp, Qb, Kb, VtT);
    attn_kernel<<<dim3(32, 16), 256, 0, stream>>>(Qb, Kb, VtT, resb);
    out_gemm_kernel<<<dim3(8, 64), 256, 0, stream>>>(
        (const u16*)Wo_bf, (const u16*)resb, bo, x, out);
    (void)Wo_bf; (void)ws_size; (void)in_sizes; (void)n_in; (void)out_size;
}

// Round 9
// 118.565 us; speedup vs baseline: 1.0237x; 1.0237x over previous
//
#include <hip/hip_runtime.h>
#include <hip/hip_bf16.h>

typedef unsigned short u16;
typedef __attribute__((ext_vector_type(8))) short frag_ab;   // 8 bf16 (4 VGPRs)
typedef __attribute__((ext_vector_type(4))) float f32x4;     // 4 fp32 acc
typedef _Float16 f16;
typedef __attribute__((ext_vector_type(4))) _Float16 f16x4;  // 4 f16 (2 VGPRs)

#define LOG2E 1.44269504088896f

__device__ __forceinline__ float fast_exp2(float x) {
    return __builtin_amdgcn_exp2f(x);   // v_exp_f32 (D = 2^S0)
}

__device__ __forceinline__ void gload_lds16(const u16* g, u16* s) {
    __builtin_amdgcn_global_load_lds((const __attribute__((address_space(1))) void*)g,
                                     (__attribute__((address_space(3))) void*)s, 16, 0, 0);
}
__device__ __forceinline__ void gload_lds16h(const f16* g, f16* s) {
    __builtin_amdgcn_global_load_lds((const __attribute__((address_space(1))) void*)g,
                                     (__attribute__((address_space(3))) void*)s, 16, 0, 0);
}

// ---------------------------------------------------------------------------
// 64x128 B^T GEMM mainloop (r7, BK=64): A=64 rows (ch), B=128 rows (pix).
// ---------------------------------------------------------------------------
__device__ __forceinline__ void gemm64x128_bt_mainloop(
    const u16* __restrict__ A, const u16* __restrict__ B, int K,
    int m0, int n0, f32x4 acc[2][4], u16* As, u16* Bs)
{
    const int tid = threadIdx.x;
    const int lane = tid & 63, quad = lane >> 4, l16 = lane & 15;
    const int wr = ((tid >> 7) & 1) * 32;
    const int wc = ((tid >> 6) & 1) * 64;
    const int srow = tid >> 3;
    const int scol = (tid & 7) * 8;

    for (int k0 = 0; k0 < K; k0 += 64) {
        __syncthreads();
        #pragma unroll
        for (int p = 0; p < 2; ++p) {
            const int r = srow + p * 32;
            gload_lds16(A + (size_t)(m0 + r) * K + k0 + scol, As + r * 64 + scol);
        }
        #pragma unroll
        for (int p = 0; p < 4; ++p) {
            const int r = srow + p * 32;
            gload_lds16(B + (size_t)(n0 + r) * K + k0 + scol, Bs + r * 64 + scol);
        }
        __syncthreads();
        #pragma unroll
        for (int ks = 0; ks < 2; ++ks) {
            frag_ab a[2], b[4];
            #pragma unroll
            for (int mt = 0; mt < 2; ++mt)
                a[mt] = *(const frag_ab*)(As + (wr + mt * 16 + l16) * 64 + ks * 32 + quad * 8);
            #pragma unroll
            for (int nt = 0; nt < 4; ++nt)
                b[nt] = *(const frag_ab*)(Bs + (wc + nt * 16 + l16) * 64 + ks * 32 + quad * 8);
            #pragma unroll
            for (int mt = 0; mt < 2; ++mt)
                #pragma unroll
                for (int nt = 0; nt < 4; ++nt)
                    acc[mt][nt] = __builtin_amdgcn_mfma_f32_16x16x32_bf16(a[mt], b[nt], acc[mt][nt], 0, 0, 0);
        }
    }
}

// ---------------------------------------------------------------------------
// 64x64 B^T GEMM mainloop (r7, BK=64) for out-proj.
// ---------------------------------------------------------------------------
__device__ __forceinline__ void gemm64x64_bt_mainloop(
    const u16* __restrict__ A, const u16* __restrict__ B, int K,
    int m0, int n0, f32x4 acc[2][2], u16* As, u16* Bs)
{
    const int tid = threadIdx.x;
    const int lane = tid & 63, quad = lane >> 4, l16 = lane & 15;
    const int wr = ((tid >> 7) & 1) * 32;
    const int wc = ((tid >> 6) & 1) * 32;
    const int srow = tid >> 3;
    const int scol = (tid & 7) * 8;

    for (int k0 = 0; k0 < K; k0 += 64) {
        __syncthreads();
        #pragma unroll
        for (int p = 0; p < 2; ++p) {
            const int r = srow + p * 32;
            gload_lds16(A + (size_t)(m0 + r) * K + k0 + scol, As + r * 64 + scol);
            gload_lds16(B + (size_t)(n0 + r) * K + k0 + scol, Bs + r * 64 + scol);
        }
        __syncthreads();
        #pragma unroll
        for (int ks = 0; ks < 2; ++ks) {
            frag_ab a[2], b[2];
            #pragma unroll
            for (int mt = 0; mt < 2; ++mt)
                a[mt] = *(const frag_ab*)(As + (wr + mt * 16 + l16) * 64 + ks * 32 + quad * 8);
            #pragma unroll
            for (int nt = 0; nt < 2; ++nt)
                b[nt] = *(const frag_ab*)(Bs + (wc + nt * 16 + l16) * 64 + ks * 32 + quad * 8);
            #pragma unroll
            for (int mt = 0; mt < 2; ++mt)
                #pragma unroll
                for (int nt = 0; nt < 2; ++nt)
                    acc[mt][nt] = __builtin_amdgcn_mfma_f32_16x16x32_bf16(a[mt], b[nt], acc[mt][nt], 0, 0, 0);
        }
    }
}

// ---------------------------------------------------------------------------
// Fused prep: blocks [0,2048): x transpose+cast; [2048,3072): W converts.
// ---------------------------------------------------------------------------
__global__ __launch_bounds__(256) void prep_kernel(
    const float* __restrict__ x, __hip_bfloat16* __restrict__ xs_bf,
    const float* __restrict__ Wp, const float* __restrict__ Wo,
    __hip_bfloat16* __restrict__ w_bf)
{
    __shared__ float tile[32][33];
    const int tid = threadIdx.x;
    const int id = blockIdx.x;
    if (id < 2048) {
        const int i0 = (id & 31) * 32;
        const int c0 = ((id >> 5) & 15) * 32;
        const int b  = id >> 9;
        const int tx = tid & 31, ty = tid >> 5;
        const float* xp = x + ((size_t)b * 512 + c0) * 1024 + i0;
        #pragma unroll
        for (int r = ty; r < 32; r += 8)
            tile[r][tx] = xp[(size_t)r * 1024 + tx];
        __syncthreads();
        __hip_bfloat16* op = xs_bf + ((size_t)b * 1024 + i0) * 512 + c0;
        #pragma unroll
        for (int r = ty; r < 32; r += 8)
            op[(size_t)r * 512 + tx] = __float2bfloat16(tile[tx][r]);
    } else {
        const int t = (id - 2048) * 256 + tid;
        const int i4 = t * 4;
        const float* src = (i4 < 786432) ? (Wp + i4) : (Wo + (i4 - 786432));
        const float4 v = *(const float4*)src;
        ushort4 o;
        o.x = __bfloat16_as_ushort(__float2bfloat16(v.x));
        o.y = __bfloat16_as_ushort(__float2bfloat16(v.y));
        o.z = __bfloat16_as_ushort(__float2bfloat16(v.z));
        o.w = __bfloat16_as_ushort(__float2bfloat16(v.w));
        *(ushort4*)((u16*)w_bf + i4) = o;
    }
}

// ---------------------------------------------------------------------------
// qkv^T GEMM (r7): 64-ch x 128-pix tiles, grid 24x32 = 768 blocks = 3/CU.
// Block's 64-ch window is exactly one of {Q,K,V} of one head (block-uniform).
// ---------------------------------------------------------------------------
__global__ __launch_bounds__(256) void qkv_gemm_kernel(
    const u16* __restrict__ Wpb, const u16* __restrict__ xsb,
    const float* __restrict__ bp,
    u16* __restrict__ Qb, u16* __restrict__ Kb, f16* __restrict__ VtT)
{
    __shared__ u16 lds[12288];      // As 4096 | Bs 8192; reused as Tr[128][72]
    u16* As = lds;
    u16* Bs = lds + 4096;
    f32x4 acc[2][4];
    #pragma unroll
    for (int mt = 0; mt < 2; ++mt)
        #pragma unroll
        for (int nt = 0; nt < 4; ++nt)
            { acc[mt][nt][0]=0.f; acc[mt][nt][1]=0.f; acc[mt][nt][2]=0.f; acc[mt][nt][3]=0.f; }
    const int m0 = blockIdx.x * 64;    // ch
    const int n0 = blockIdx.y * 128;   // pix
    gemm64x128_bt_mainloop(Wpb, xsb, 512, m0, n0, acc, As, Bs);

    const int tid = threadIdx.x;
    const int lane = tid & 63, quad = lane >> 4, l16 = lane & 15;
    const int wr = ((tid >> 7) & 1) * 32, wc = ((tid >> 6) & 1) * 64;
    const int h = blockIdx.x / 3, part = blockIdx.x % 3;   // block-uniform
    const int b = blockIdx.y >> 3, ipb = (blockIdx.y & 7) * 128;
    const size_t bh = (size_t)(b * 8 + h);

    if (part < 2) {
        const float scale = (part == 0) ? (0.125f * LOG2E) : 1.0f;
        __syncthreads();            // all waves done with As/Bs
        u16* T = lds;               // [pix 128][ch 64 pad 72]
        #pragma unroll
        for (int nt = 0; nt < 4; ++nt) {
            const int px = wc + nt * 16 + l16;
            #pragma unroll
            for (int mt = 0; mt < 2; ++mt) {
                const int cb = m0 + wr + mt * 16 + quad * 4;
                ushort4 pk;
                pk.x = __bfloat16_as_ushort(__float2bfloat16((acc[mt][nt][0] + bp[cb + 0]) * scale));
                pk.y = __bfloat16_as_ushort(__float2bfloat16((acc[mt][nt][1] + bp[cb + 1]) * scale));
                pk.z = __bfloat16_as_ushort(__float2bfloat16((acc[mt][nt][2] + bp[cb + 2]) * scale));
                pk.w = __bfloat16_as_ushort(__float2bfloat16((acc[mt][nt][3] + bp[cb + 3]) * scale));
                *(ushort4*)&T[px * 72 + wr + mt * 16 + quad * 4] = pk;
            }
        }
        __syncthreads();
        u16* dst = (part == 0 ? Qb : Kb);
        #pragma unroll
        for (int p = 0; p < 4; ++p) {
            const int row = p * 32 + (tid >> 3);
            const int ch8 = (tid & 7) * 8;
            uint4 rv = *(uint4*)&T[row * 72 + ch8];
            *(uint4*)(dst + ((bh * 1024 + ipb + row) << 6) + ch8) = rv;
        }
    } else {
        f16* dst = VtT + bh * 65536;   // [jc 128][d 64][j8 8]
        #pragma unroll
        for (int mt = 0; mt < 2; ++mt) {
            #pragma unroll
            for (int r = 0; r < 4; ++r) {
                const int d = wr + mt * 16 + quad * 4 + r;
                const float bias = bp[m0 + d];
                #pragma unroll
                for (int nt = 0; nt < 4; ++nt) {
                    const int j = ipb + wc + nt * 16 + l16;
                    dst[(size_t)(j >> 3) * 512 + d * 8 + (j & 7)] =
                        (f16)(acc[mt][nt][r] + bias);
                }
            }
        }
    }
}

// ---------------------------------------------------------------------------
// Attention v4: block = (bh, 32-row i-tile) -> grid 32x32 = 1024 blocks
// (4.0 blocks/CU exact). 4 waves split j (32-j windows), each computing both
// 16-row i-groups from resident Q frags. Combine staging OVERLAYS the dead
// Ks/Vs pool after the j-loop -> LDS ~33 KB, so all 4 blocks/CU fit.
// ---------------------------------------------------------------------------
__global__ __launch_bounds__(256) void attn_kernel(
    const u16* __restrict__ Qb, const u16* __restrict__ Kb,
    const f16* __restrict__ VtT, __hip_bfloat16* __restrict__ resb)
{
    __shared__ u16 pool[16384];           // 32 KB: Ks[0:8192] | Vs[8192:16384]
    __shared__ float Lpart[4][2][16];     // [w][ig][i]
    u16* Ks = pool;                       // [j_local 128][d 64]
    f16* Vs = (f16*)(pool + 8192);        // [chunk 16][d 64][j8 8]
    const int bh = blockIdx.x;
    const int it = blockIdx.y;            // 32-row i tile, 0..31
    const int tid = threadIdx.x;
    const int w = tid >> 6, lane = tid & 63, quad = lane >> 4, l16 = lane & 15;
    const int srow = tid >> 3, scol = (tid & 7) * 8;

    const u16* Qp = Qb + (size_t)bh * 65536;
    const u16* Kp = Kb + (size_t)bh * 65536;
    const f16* Vp = VtT + (size_t)bh * 65536;

    frag_ab bq[2][2];
    #pragma unroll
    for (int ig = 0; ig < 2; ++ig) {
        const u16* qptr = Qp + (size_t)(it * 32 + ig * 16 + l16) * 64 + quad * 8;
        bq[ig][0] = *(const frag_ab*)(qptr);
        bq[ig][1] = *(const frag_ab*)(qptr + 32);
    }

    f32x4 o[2][4];
    #pragma unroll
    for (int ig = 0; ig < 2; ++ig)
        #pragma unroll
        for (int dt = 0; dt < 4; ++dt)
            { o[ig][dt][0]=0.f; o[ig][dt][1]=0.f; o[ig][dt][2]=0.f; o[ig][dt][3]=0.f; }
    float l_acc[2] = {0.f, 0.f};

    for (int jt = 0; jt < 8; ++jt) {
        __syncthreads();
        #pragma unroll
        for (int p = 0; p < 4; ++p) {
            const int r = srow + p * 32;
            gload_lds16(Kp + (size_t)(jt * 128 + r) * 64 + scol, Ks + r * 64 + scol);
        }
        #pragma unroll
        for (int p = 0; p < 4; ++p) {
            const int c = w * 4 + p;
            gload_lds16h(Vp + (size_t)((jt * 16 + c) * 64 + lane) * 8,
                         Vs + (size_t)(c * 64 + lane) * 8);
        }
        __syncthreads();

        frag_ab ka[2][2];
        #pragma unroll
        for (int mt = 0; mt < 2; ++mt) {
            const u16* kp = Ks + (w * 32 + mt * 16 + l16) * 64 + quad * 8;
            ka[mt][0] = *(const frag_ab*)(kp);
            ka[mt][1] = *(const frag_ab*)(kp + 32);
        }
        f16x4 va[4][2];
        #pragma unroll
        for (int ks = 0; ks < 2; ++ks) {
            const f16* vrow = Vs + (size_t)(w * 4 + ks * 2 + (quad >> 1)) * 512 + (quad & 1) * 4;
            #pragma unroll
            for (int dt = 0; dt < 4; ++dt)
                va[dt][ks] = *(const f16x4*)(vrow + (dt * 16 + l16) * 8);
        }
        #pragma unroll
        for (int ig = 0; ig < 2; ++ig) {
            f32x4 st0 = {0.f, 0.f, 0.f, 0.f}, st1 = {0.f, 0.f, 0.f, 0.f};
            st0 = __builtin_amdgcn_mfma_f32_16x16x32_bf16(ka[0][0], bq[ig][0], st0, 0, 0, 0);
            st0 = __builtin_amdgcn_mfma_f32_16x16x32_bf16(ka[0][1], bq[ig][1], st0, 0, 0, 0);
            st1 = __builtin_amdgcn_mfma_f32_16x16x32_bf16(ka[1][0], bq[ig][0], st1, 0, 0, 0);
            st1 = __builtin_amdgcn_mfma_f32_16x16x32_bf16(ka[1][1], bq[ig][1], st1, 0, 0, 0);
            f16x4 p0, p1;
            float s = 0.f;
            #pragma unroll
            for (int r = 0; r < 4; ++r) {
                const float e0 = fast_exp2(st0[r]);
                const float e1 = fast_exp2(st1[r]);
                s += e0 + e1;
                p0[r] = (f16)e0;
                p1[r] = (f16)e1;
            }
            l_acc[ig] += s;
            #pragma unroll
            for (int dt = 0; dt < 4; ++dt) {
                o[ig][dt] = __builtin_amdgcn_mfma_f32_16x16x16f16(va[dt][0], p0, o[ig][dt], 0, 0, 0);
                o[ig][dt] = __builtin_amdgcn_mfma_f32_16x16x16f16(va[dt][1], p1, o[ig][dt], 0, 0, 0);
            }
        }
    }
    #pragma unroll
    for (int ig = 0; ig < 2; ++ig) {
        l_acc[ig] += __shfl_xor(l_acc[ig], 16);
        l_acc[ig] += __shfl_xor(l_acc[ig], 32);
    }
    if (lane < 16) {
        #pragma unroll
        for (int ig = 0; ig < 2; ++ig)
            Lpart[w][ig][lane] = l_acc[ig];
    }

    // 2-phase combine overlaid on pool: Op[4][16][68] fp32 = 17.4 KB <= 32 KB
    float* Op = (float*)pool;
    const int bb = bh >> 3, hh = bh & 7;
    const int ri = tid >> 4, d0f = (tid & 15) * 4;
    #pragma unroll
    for (int ph = 0; ph < 2; ++ph) {
        __syncthreads();   // ph0: Ks/Vs reads + Lpart done; ph1: prior reads done
        #pragma unroll
        for (int dt = 0; dt < 4; ++dt)
            *(f32x4*)&Op[(w * 16 + l16) * 68 + dt * 16 + quad * 4] = o[ph][dt];
        __syncthreads();
        f32x4 s = *(const f32x4*)&Op[ri * 68 + d0f];
        #pragma unroll
        for (int ww = 1; ww < 4; ++ww)
            s += *(const f32x4*)&Op[(ww * 16 + ri) * 68 + d0f];
        const float linv = 1.f / (Lpart[0][ph][ri] + Lpart[1][ph][ri] +
                                  Lpart[2][ph][ri] + Lpart[3][ph][ri]);
        u16 pk[4];
        #pragma unroll
        for (int e = 0; e < 4; ++e)
            pk[e] = __bfloat16_as_ushort(__float2bfloat16(s[e] * linv));
        u16* orow = (u16*)resb +
            ((size_t)(bb * 1024 + it * 32 + ph * 16 + ri)) * 512 + hh * 64 + d0f;
        *(uint2*)orow = *(uint2*)pk;
    }
}

// ---------------------------------------------------------------------------
// out^T GEMM (r7): 64x64 tiles, grid 8x64 = 512 blocks = 2/CU.
// D[c][pix] = Wo[c,:].res[pix,:] + bo[c] + x[b][c][pix]
// ---------------------------------------------------------------------------
__global__ __launch_bounds__(256) void out_gemm_kernel(
    const u16* __restrict__ Wob, const u16* __restrict__ resb,
    const float* __restrict__ bo, const float* __restrict__ x,
    float* __restrict__ out)
{
    __shared__ u16 As[64 * 64];
    __shared__ u16 Bs[64 * 64];
    f32x4 acc[2][2];
    #pragma unroll
    for (int mt = 0; mt < 2; ++mt)
        #pragma unroll
        for (int nt = 0; nt < 2; ++nt)
            { acc[mt][nt][0]=0.f; acc[mt][nt][1]=0.f; acc[mt][nt][2]=0.f; acc[mt][nt][3]=0.f; }
    const int m0 = blockIdx.x * 64;   // c
    const int n0 = blockIdx.y * 64;   // pix
    gemm64x64_bt_mainloop(Wob, resb, 512, m0, n0, acc, As, Bs);

    const int tid = threadIdx.x;
    const int lane = tid & 63, quad = lane >> 4, l16 = lane & 15;
    const int wr = ((tid >> 7) & 1) * 32, wc = ((tid >> 6) & 1) * 32;
    #pragma unroll
    for (int nt = 0; nt < 2; ++nt) {
        const int pix = n0 + wc + nt * 16 + l16;
        const int b = pix >> 10, ip = pix & 1023;
        #pragma unroll
        for (int mt = 0; mt < 2; ++mt) {
            #pragma unroll
            for (int r = 0; r < 4; ++r) {
                const int c = m0 + wr + mt * 16 + quad * 4 + r;
                const size_t oidx = (((size_t)b * 512 + c) << 10) + ip;
                out[oidx] = acc[mt][nt][r] + bo[c] + x[oidx];
            }
        }
    }
}

// ---------------------------------------------------------------------------
extern "C" void kernel_launch(void* const* d_in, const int* in_sizes, int n_in,
                              void* d_out, int out_size, void* d_ws, size_t ws_size,
                              hipStream_t stream)
{
    const float* x  = (const float*)d_in[0];   // [4,512,32,32]
    const float* Wp = (const float*)d_in[1];   // [1536,512]
    const float* bp = (const float*)d_in[2];   // [1536]
    const float* Wo = (const float*)d_in[3];   // [512,512]
    const float* bo = (const float*)d_in[4];   // [512]
    float* out = (float*)d_out;

    char* ws = (char*)d_ws;
    size_t off = 0;
    auto carve = [&](size_t bytes) -> void* {
        void* ptr = ws + off;
        off += (bytes + 255) & ~(size_t)255;
        return ptr;
    };
    __hip_bfloat16* xs_bf = (__hip_bfloat16*)carve((size_t)4096 * 512 * 2);
    __hip_bfloat16* Wp_bf = (__hip_bfloat16*)carve((size_t)1536 * 512 * 2);  // Wo_bf contiguous after
    __hip_bfloat16* Wo_bf = (__hip_bfloat16*)carve((size_t)512 * 512 * 2);
    u16*            Qb    = (u16*)carve((size_t)32 * 1024 * 64 * 2);
    u16*            Kb    = (u16*)carve((size_t)32 * 1024 * 64 * 2);
    f16*            VtT   = (f16*)carve((size_t)32 * 1024 * 64 * 2);
    __hip_bfloat16* resb  = (__hip_bfloat16*)carve((size_t)4096 * 512 * 2);

    prep_kernel<<<dim3(3072), 256, 0, stream>>>(x, xs_bf, Wp, Wo, Wp_bf);
    qkv_gemm_kernel<<<dim3(24, 32), 256, 0, stream>>>(
        (const u16*)Wp_bf, (const u16*)xs_bf, bp, Qb, Kb, VtT);
    attn_kernel<<<dim3(32, 32), 256, 0, stream>>>(Qb, Kb, VtT, resb);
    out_gemm_kernel<<<dim3(8, 64), 256, 0, stream>>>(
        (const u16*)Wo_bf, (const u16*)resb, bo, x, out);
    (void)Wo_bf; (void)ws_size; (void)in_sizes; (void)n_in; (void)out_size;
}

// Round 10
// 113.224 us; speedup vs baseline: 1.0720x; 1.0472x over previous
//
#include <hip/hip_runtime.h>
#include <hip/hip_bf16.h>

typedef unsigned short u16;
typedef __attribute__((ext_vector_type(8))) short frag_ab;   // 8 bf16 (4 VGPRs)
typedef __attribute__((ext_vector_type(4))) float f32x4;     // 4 fp32 acc
typedef _Float16 f16;
typedef __attribute__((ext_vector_type(4))) _Float16 f16x4;  // 4 f16 (2 VGPRs)

#define LOG2E 1.44269504088896f

__device__ __forceinline__ float fast_exp2(float x) {
    return __builtin_amdgcn_exp2f(x);   // v_exp_f32 (D = 2^S0)
}

__device__ __forceinline__ void gload_lds16(const u16* g, u16* s) {
    __builtin_amdgcn_global_load_lds((const __attribute__((address_space(1))) void*)g,
                                     (__attribute__((address_space(3))) void*)s, 16, 0, 0);
}
__device__ __forceinline__ void gload_lds16h(const f16* g, f16* s) {
    __builtin_amdgcn_global_load_lds((const __attribute__((address_space(1))) void*)g,
                                     (__attribute__((address_space(3))) void*)s, 16, 0, 0);
}

// ---------------------------------------------------------------------------
// 64x128 B^T GEMM mainloop (BK=64): A=64 rows (ch), B=128 rows (pix).
// ---------------------------------------------------------------------------
__device__ __forceinline__ void gemm64x128_bt_mainloop(
    const u16* __restrict__ A, const u16* __restrict__ B, int K,
    int m0, int n0, f32x4 acc[2][4], u16* As, u16* Bs)
{
    const int tid = threadIdx.x;
    const int lane = tid & 63, quad = lane >> 4, l16 = lane & 15;
    const int wr = ((tid >> 7) & 1) * 32;
    const int wc = ((tid >> 6) & 1) * 64;
    const int srow = tid >> 3;
    const int scol = (tid & 7) * 8;

    for (int k0 = 0; k0 < K; k0 += 64) {
        __syncthreads();
        #pragma unroll
        for (int p = 0; p < 2; ++p) {
            const int r = srow + p * 32;
            gload_lds16(A + (size_t)(m0 + r) * K + k0 + scol, As + r * 64 + scol);
        }
        #pragma unroll
        for (int p = 0; p < 4; ++p) {
            const int r = srow + p * 32;
            gload_lds16(B + (size_t)(n0 + r) * K + k0 + scol, Bs + r * 64 + scol);
        }
        __syncthreads();
        #pragma unroll
        for (int ks = 0; ks < 2; ++ks) {
            frag_ab a[2], b[4];
            #pragma unroll
            for (int mt = 0; mt < 2; ++mt)
                a[mt] = *(const frag_ab*)(As + (wr + mt * 16 + l16) * 64 + ks * 32 + quad * 8);
            #pragma unroll
            for (int nt = 0; nt < 4; ++nt)
                b[nt] = *(const frag_ab*)(Bs + (wc + nt * 16 + l16) * 64 + ks * 32 + quad * 8);
            #pragma unroll
            for (int mt = 0; mt < 2; ++mt)
                #pragma unroll
                for (int nt = 0; nt < 4; ++nt)
                    acc[mt][nt] = __builtin_amdgcn_mfma_f32_16x16x32_bf16(a[mt], b[nt], acc[mt][nt], 0, 0, 0);
        }
    }
}

// ---------------------------------------------------------------------------
// 64x64 B^T GEMM mainloop (BK=64) for out-proj.
// ---------------------------------------------------------------------------
__device__ __forceinline__ void gemm64x64_bt_mainloop(
    const u16* __restrict__ A, const u16* __restrict__ B, int K,
    int m0, int n0, f32x4 acc[2][2], u16* As, u16* Bs)
{
    const int tid = threadIdx.x;
    const int lane = tid & 63, quad = lane >> 4, l16 = lane & 15;
    const int wr = ((tid >> 7) & 1) * 32;
    const int wc = ((tid >> 6) & 1) * 32;
    const int srow = tid >> 3;
    const int scol = (tid & 7) * 8;

    for (int k0 = 0; k0 < K; k0 += 64) {
        __syncthreads();
        #pragma unroll
        for (int p = 0; p < 2; ++p) {
            const int r = srow + p * 32;
            gload_lds16(A + (size_t)(m0 + r) * K + k0 + scol, As + r * 64 + scol);
            gload_lds16(B + (size_t)(n0 + r) * K + k0 + scol, Bs + r * 64 + scol);
        }
        __syncthreads();
        #pragma unroll
        for (int ks = 0; ks < 2; ++ks) {
            frag_ab a[2], b[2];
            #pragma unroll
            for (int mt = 0; mt < 2; ++mt)
                a[mt] = *(const frag_ab*)(As + (wr + mt * 16 + l16) * 64 + ks * 32 + quad * 8);
            #pragma unroll
            for (int nt = 0; nt < 2; ++nt)
                b[nt] = *(const frag_ab*)(Bs + (wc + nt * 16 + l16) * 64 + ks * 32 + quad * 8);
            #pragma unroll
            for (int mt = 0; mt < 2; ++mt)
                #pragma unroll
                for (int nt = 0; nt < 2; ++nt)
                    acc[mt][nt] = __builtin_amdgcn_mfma_f32_16x16x32_bf16(a[mt], b[nt], acc[mt][nt], 0, 0, 0);
        }
    }
}

// ---------------------------------------------------------------------------
// Fused prep: blocks [0,2048): x transpose+cast; [2048,3072): W converts.
// ---------------------------------------------------------------------------
__global__ __launch_bounds__(256) void prep_kernel(
    const float* __restrict__ x, __hip_bfloat16* __restrict__ xs_bf,
    const float* __restrict__ Wp, const float* __restrict__ Wo,
    __hip_bfloat16* __restrict__ w_bf)
{
    __shared__ float tile[32][33];
    const int tid = threadIdx.x;
    const int id = blockIdx.x;
    if (id < 2048) {
        const int i0 = (id & 31) * 32;
        const int c0 = ((id >> 5) & 15) * 32;
        const int b  = id >> 9;
        const int tx = tid & 31, ty = tid >> 5;
        const float* xp = x + ((size_t)b * 512 + c0) * 1024 + i0;
        #pragma unroll
        for (int r = ty; r < 32; r += 8)
            tile[r][tx] = xp[(size_t)r * 1024 + tx];
        __syncthreads();
        __hip_bfloat16* op = xs_bf + ((size_t)b * 1024 + i0) * 512 + c0;
        #pragma unroll
        for (int r = ty; r < 32; r += 8)
            op[(size_t)r * 512 + tx] = __float2bfloat16(tile[tx][r]);
    } else {
        const int t = (id - 2048) * 256 + tid;
        const int i4 = t * 4;
        const float* src = (i4 < 786432) ? (Wp + i4) : (Wo + (i4 - 786432));
        const float4 v = *(const float4*)src;
        ushort4 o;
        o.x = __bfloat16_as_ushort(__float2bfloat16(v.x));
        o.y = __bfloat16_as_ushort(__float2bfloat16(v.y));
        o.z = __bfloat16_as_ushort(__float2bfloat16(v.z));
        o.w = __bfloat16_as_ushort(__float2bfloat16(v.w));
        *(ushort4*)((u16*)w_bf + i4) = o;
    }
}

// ---------------------------------------------------------------------------
// qkv^T GEMM: 64-ch x 128-pix tiles, grid (32 pix-windows, 24 ch-tiles)
// = 768 blocks = 3/CU, no tail. Grid dims are swapped vs r7 so blocks
// sharing the same Bs (xs pix-window) are 32 apart in dispatch order ->
// same XCD (32%8==0): per-XCD L2 working set ~2 MB instead of ~4 MB.
// Block's 64-ch window is exactly one of {Q,K,V} of one head (block-uniform).
// ---------------------------------------------------------------------------
__global__ __launch_bounds__(256) void qkv_gemm_kernel(
    const u16* __restrict__ Wpb, const u16* __restrict__ xsb,
    const float* __restrict__ bp,
    u16* __restrict__ Qb, u16* __restrict__ Kb, f16* __restrict__ VtT)
{
    __shared__ u16 lds[12288];      // As 4096 | Bs 8192; reused as Tr[128][72]
    u16* As = lds;
    u16* Bs = lds + 4096;
    f32x4 acc[2][4];
    #pragma unroll
    for (int mt = 0; mt < 2; ++mt)
        #pragma unroll
        for (int nt = 0; nt < 4; ++nt)
            { acc[mt][nt][0]=0.f; acc[mt][nt][1]=0.f; acc[mt][nt][2]=0.f; acc[mt][nt][3]=0.f; }
    const int m0 = blockIdx.y * 64;    // ch   (y: 0..23)
    const int n0 = blockIdx.x * 128;   // pix  (x: 0..31)
    gemm64x128_bt_mainloop(Wpb, xsb, 512, m0, n0, acc, As, Bs);

    const int tid = threadIdx.x;
    const int lane = tid & 63, quad = lane >> 4, l16 = lane & 15;
    const int wr = ((tid >> 7) & 1) * 32, wc = ((tid >> 6) & 1) * 64;
    const int h = blockIdx.y / 3, part = blockIdx.y % 3;   // block-uniform
    const int b = blockIdx.x >> 3, ipb = (blockIdx.x & 7) * 128;
    const size_t bh = (size_t)(b * 8 + h);

    if (part < 2) {
        const float scale = (part == 0) ? (0.125f * LOG2E) : 1.0f;
        __syncthreads();            // all waves done with As/Bs
        u16* T = lds;               // [pix 128][ch 64 pad 72]
        #pragma unroll
        for (int nt = 0; nt < 4; ++nt) {
            const int px = wc + nt * 16 + l16;
            #pragma unroll
            for (int mt = 0; mt < 2; ++mt) {
                const int cb = m0 + wr + mt * 16 + quad * 4;
                ushort4 pk;
                pk.x = __bfloat16_as_ushort(__float2bfloat16((acc[mt][nt][0] + bp[cb + 0]) * scale));
                pk.y = __bfloat16_as_ushort(__float2bfloat16((acc[mt][nt][1] + bp[cb + 1]) * scale));
                pk.z = __bfloat16_as_ushort(__float2bfloat16((acc[mt][nt][2] + bp[cb + 2]) * scale));
                pk.w = __bfloat16_as_ushort(__float2bfloat16((acc[mt][nt][3] + bp[cb + 3]) * scale));
                *(ushort4*)&T[px * 72 + wr + mt * 16 + quad * 4] = pk;
            }
        }
        __syncthreads();
        u16* dst = (part == 0 ? Qb : Kb);
        #pragma unroll
        for (int p = 0; p < 4; ++p) {
            const int row = p * 32 + (tid >> 3);
            const int ch8 = (tid & 7) * 8;
            uint4 rv = *(uint4*)&T[row * 72 + ch8];
            *(uint4*)(dst + ((bh * 1024 + ipb + row) << 6) + ch8) = rv;
        }
    } else {
        f16* dst = VtT + bh * 65536;   // [jc 128][d 64][j8 8]
        #pragma unroll
        for (int mt = 0; mt < 2; ++mt) {
            #pragma unroll
            for (int r = 0; r < 4; ++r) {
                const int d = wr + mt * 16 + quad * 4 + r;
                const float bias = bp[m0 + d];
                #pragma unroll
                for (int nt = 0; nt < 4; ++nt) {
                    const int j = ipb + wc + nt * 16 + l16;
                    dst[(size_t)(j >> 3) * 512 + d * 8 + (j & 7)] =
                        (f16)(acc[mt][nt][r] + bias);
                }
            }
        }
    }
}

// ---------------------------------------------------------------------------
// Attention (r7/v3, best measured): block = (bh, 64-i tile) -> 512 blocks,
// 4 waves split j (32-j windows), all-64-i Q frags resident per wave.
// Max-free softmax (exp2 form) => j-partials additive; 2-phase fp32 combine.
// ---------------------------------------------------------------------------
__global__ __launch_bounds__(256) void attn_kernel(
    const u16* __restrict__ Qb, const u16* __restrict__ Kb,
    const f16* __restrict__ VtT, __hip_bfloat16* __restrict__ resb)
{
    __shared__ u16 Ks[128 * 64];          // 16 KB [j_local][d]
    __shared__ f16 Vs[16 * 64 * 8];       // 16 KB [chunk][d][j8]
    __shared__ float Opart[4][32][68];    // 34.8 KB combine staging
    __shared__ float Lpart[4][4][16];     // 1 KB [w][ig][i]
    const int bh = blockIdx.x;
    const int it = blockIdx.y;            // 64-row i tile, 0..15
    const int tid = threadIdx.x;
    const int w = tid >> 6, lane = tid & 63, quad = lane >> 4, l16 = lane & 15;
    const int srow = tid >> 3, scol = (tid & 7) * 8;

    const u16* Qp = Qb + (size_t)bh * 65536;
    const u16* Kp = Kb + (size_t)bh * 65536;
    const f16* Vp = VtT + (size_t)bh * 65536;

    frag_ab bq[4][2];
    #pragma unroll
    for (int ig = 0; ig < 4; ++ig) {
        const u16* qptr = Qp + (size_t)(it * 64 + ig * 16 + l16) * 64 + quad * 8;
        bq[ig][0] = *(const frag_ab*)(qptr);
        bq[ig][1] = *(const frag_ab*)(qptr + 32);
    }

    f32x4 o[4][4];
    #pragma unroll
    for (int ig = 0; ig < 4; ++ig)
        #pragma unroll
        for (int dt = 0; dt < 4; ++dt)
            { o[ig][dt][0]=0.f; o[ig][dt][1]=0.f; o[ig][dt][2]=0.f; o[ig][dt][3]=0.f; }
    float l_acc[4] = {0.f, 0.f, 0.f, 0.f};

    for (int jt = 0; jt < 8; ++jt) {
        __syncthreads();
        #pragma unroll
        for (int p = 0; p < 4; ++p) {
            const int r = srow + p * 32;
            gload_lds16(Kp + (size_t)(jt * 128 + r) * 64 + scol, Ks + r * 64 + scol);
        }
        #pragma unroll
        for (int p = 0; p < 4; ++p) {
            const int c = w * 4 + p;
            gload_lds16h(Vp + (size_t)((jt * 16 + c) * 64 + lane) * 8,
                         Vs + (size_t)(c * 64 + lane) * 8);
        }
        __syncthreads();

        frag_ab ka[2][2];
        #pragma unroll
        for (int mt = 0; mt < 2; ++mt) {
            const u16* kp = Ks + (w * 32 + mt * 16 + l16) * 64 + quad * 8;
            ka[mt][0] = *(const frag_ab*)(kp);
            ka[mt][1] = *(const frag_ab*)(kp + 32);
        }
        f16x4 va[4][2];
        #pragma unroll
        for (int ks = 0; ks < 2; ++ks) {
            const f16* vrow = Vs + (size_t)(w * 4 + ks * 2 + (quad >> 1)) * 512 + (quad & 1) * 4;
            #pragma unroll
            for (int dt = 0; dt < 4; ++dt)
                va[dt][ks] = *(const f16x4*)(vrow + (dt * 16 + l16) * 8);
        }
        #pragma unroll
        for (int ig = 0; ig < 4; ++ig) {
            f32x4 st0 = {0.f, 0.f, 0.f, 0.f}, st1 = {0.f, 0.f, 0.f, 0.f};
            st0 = __builtin_amdgcn_mfma_f32_16x16x32_bf16(ka[0][0], bq[ig][0], st0, 0, 0, 0);
            st0 = __builtin_amdgcn_mfma_f32_16x16x32_bf16(ka[0][1], bq[ig][1], st0, 0, 0, 0);
            st1 = __builtin_amdgcn_mfma_f32_16x16x32_bf16(ka[1][0], bq[ig][0], st1, 0, 0, 0);
            st1 = __builtin_amdgcn_mfma_f32_16x16x32_bf16(ka[1][1], bq[ig][1], st1, 0, 0, 0);
            f16x4 p0, p1;
            float s = 0.f;
            #pragma unroll
            for (int r = 0; r < 4; ++r) {
                const float e0 = fast_exp2(st0[r]);
                const float e1 = fast_exp2(st1[r]);
                s += e0 + e1;
                p0[r] = (f16)e0;
                p1[r] = (f16)e1;
            }
            l_acc[ig] += s;
            #pragma unroll
            for (int dt = 0; dt < 4; ++dt) {
                o[ig][dt] = __builtin_amdgcn_mfma_f32_16x16x16f16(va[dt][0], p0, o[ig][dt], 0, 0, 0);
                o[ig][dt] = __builtin_amdgcn_mfma_f32_16x16x16f16(va[dt][1], p1, o[ig][dt], 0, 0, 0);
            }
        }
    }
    #pragma unroll
    for (int ig = 0; ig < 4; ++ig) {
        l_acc[ig] += __shfl_xor(l_acc[ig], 16);
        l_acc[ig] += __shfl_xor(l_acc[ig], 32);
    }
    if (lane < 16) {
        #pragma unroll
        for (int ig = 0; ig < 4; ++ig)
            Lpart[w][ig][lane] = l_acc[ig];
    }

    const int bb = bh >> 3, hh = bh & 7;
    const int il = tid >> 3, d0 = (tid & 7) * 8;
    #pragma unroll
    for (int ph = 0; ph < 2; ++ph) {
        __syncthreads();
        #pragma unroll
        for (int g = 0; g < 2; ++g) {
            const int ig = ph * 2 + g;
            #pragma unroll
            for (int dt = 0; dt < 4; ++dt)
                *(f32x4*)&Opart[w][g * 16 + l16][dt * 16 + quad * 4] = o[ig][dt];
        }
        __syncthreads();
        f32x4 sa = *(const f32x4*)&Opart[0][il][d0];
        f32x4 sb = *(const f32x4*)&Opart[0][il][d0 + 4];
        #pragma unroll
        for (int ww = 1; ww < 4; ++ww) {
            sa += *(const f32x4*)&Opart[ww][il][d0];
            sb += *(const f32x4*)&Opart[ww][il][d0 + 4];
        }
        const int ig = ph * 2 + (il >> 4);
        const float linv = 1.f / (Lpart[0][ig][il & 15] + Lpart[1][ig][il & 15] +
                                  Lpart[2][ig][il & 15] + Lpart[3][ig][il & 15]);
        u16 pk[8];
        #pragma unroll
        for (int e = 0; e < 4; ++e) {
            pk[e]     = __bfloat16_as_ushort(__float2bfloat16(sa[e] * linv));
            pk[e + 4] = __bfloat16_as_ushort(__float2bfloat16(sb[e] * linv));
        }
        u16* orow = (u16*)resb +
            ((size_t)(bb * 1024 + it * 64 + ph * 32 + il)) * 512 + hh * 64 + d0;
        *(uint4*)orow = *(uint4*)pk;
    }
}

// ---------------------------------------------------------------------------
// out^T GEMM: 64x64 tiles, grid 8x64 = 512 blocks = 2/CU.
// D[c][pix] = Wo[c,:].res[pix,:] + bo[c] + x[b][c][pix]
// ---------------------------------------------------------------------------
__global__ __launch_bounds__(256) void out_gemm_kernel(
    const u16* __restrict__ Wob, const u16* __restrict__ resb,
    const float* __restrict__ bo, const float* __restrict__ x,
    float* __restrict__ out)
{
    __shared__ u16 As[64 * 64];
    __shared__ u16 Bs[64 * 64];
    f32x4 acc[2][2];
    #pragma unroll
    for (int mt = 0; mt < 2; ++mt)
        #pragma unroll
        for (int nt = 0; nt < 2; ++nt)
            { acc[mt][nt][0]=0.f; acc[mt][nt][1]=0.f; acc[mt][nt][2]=0.f; acc[mt][nt][3]=0.f; }
    const int m0 = blockIdx.x * 64;   // c
    const int n0 = blockIdx.y * 64;   // pix
    gemm64x64_bt_mainloop(Wob, resb, 512, m0, n0, acc, As, Bs);

    const int tid = threadIdx.x;
    const int lane = tid & 63, quad = lane >> 4, l16 = lane & 15;
    const int wr = ((tid >> 7) & 1) * 32, wc = ((tid >> 6) & 1) * 32;
    #pragma unroll
    for (int nt = 0; nt < 2; ++nt) {
        const int pix = n0 + wc + nt * 16 + l16;
        const int b = pix >> 10, ip = pix & 1023;
        #pragma unroll
        for (int mt = 0; mt < 2; ++mt) {
            #pragma unroll
            for (int r = 0; r < 4; ++r) {
                const int c = m0 + wr + mt * 16 + quad * 4 + r;
                const size_t oidx = (((size_t)b * 512 + c) << 10) + ip;
                out[oidx] = acc[mt][nt][r] + bo[c] + x[oidx];
            }
        }
    }
}

// ---------------------------------------------------------------------------
extern "C" void kernel_launch(void* const* d_in, const int* in_sizes, int n_in,
                              void* d_out, int out_size, void* d_ws, size_t ws_size,
                              hipStream_t stream)
{
    const float* x  = (const float*)d_in[0];   // [4,512,32,32]
    const float* Wp = (const float*)d_in[1];   // [1536,512]
    const float* bp = (const float*)d_in[2];   // [1536]
    const float* Wo = (const float*)d_in[3];   // [512,512]
    const float* bo = (const float*)d_in[4];   // [512]
    float* out = (float*)d_out;

    char* ws = (char*)d_ws;
    size_t off = 0;
    auto carve = [&](size_t bytes) -> void* {
        void* ptr = ws + off;
        off += (bytes + 255) & ~(size_t)255;
        return ptr;
    };
    __hip_bfloat16* xs_bf = (__hip_bfloat16*)carve((size_t)4096 * 512 * 2);
    __hip_bfloat16* Wp_bf = (__hip_bfloat16*)carve((size_t)1536 * 512 * 2);  // Wo_bf contiguous after
    __hip_bfloat16* Wo_bf = (__hip_bfloat16*)carve((size_t)512 * 512 * 2);
    u16*            Qb    = (u16*)carve((size_t)32 * 1024 * 64 * 2);
    u16*            Kb    = (u16*)carve((size_t)32 * 1024 * 64 * 2);
    f16*            VtT   = (f16*)carve((size_t)32 * 1024 * 64 * 2);
    __hip_bfloat16* resb  = (__hip_bfloat16*)carve((size_t)4096 * 512 * 2);

    prep_kernel<<<dim3(3072), 256, 0, stream>>>(x, xs_bf, Wp, Wo, Wp_bf);
    qkv_gemm_kernel<<<dim3(32, 24), 256, 0, stream>>>(
        (const u16*)Wp_bf, (const u16*)xs_bf, bp, Qb, Kb, VtT);
    attn_kernel<<<dim3(32, 16), 256, 0, stream>>>(Qb, Kb, VtT, resb);
    out_gemm_kernel<<<dim3(8, 64), 256, 0, stream>>>(
        (const u16*)Wo_bf, (const u16*)resb, bo, x, out);
    (void)Wo_bf; (void)ws_size; (void)in_sizes; (void)n_in; (void)out_size;
}